// Round 1
// baseline (3418.769 us; speedup 1.0000x reference)
//
#include <hip/hip_runtime.h>

// ---------------- problem constants ----------------
#define E_NODES 62
#define TOPK 10
// conv geometry: (5,64) -> c1 5x5 -> (1,60) -> pool -> 30
//                -> c2 1x5 (32ch) -> 26 -> pool -> 13
//                -> c3 1x5 (64ch) -> 9 -> pool -> 4   (position 8 unused)

// ================= fused conv chain =================
// 256 threads / block, 4 images per block.
// LDS floats: img[4][320] @0 | h1[4][32][32] @1280 | h2[4][64][16] @5376 | wbuf @9472 (20864)
#define CONV_LDS_FLOATS 30336
#define CONV_LDS_BYTES (CONV_LDS_FLOATS * 4)

__global__ __launch_bounds__(256) void conv_chain_kernel(
    const float* __restrict__ x,
    const float* __restrict__ w1, const float* __restrict__ b1,
    const float* __restrict__ w2, const float* __restrict__ b2,
    const float* __restrict__ w3, const float* __restrict__ b3,
    float* __restrict__ H3)
{
  extern __shared__ float sm[];
  float* s_img = sm;           // 4*320
  float* s_h1  = sm + 1280;    // 4*32*32 (pitch 32, 30 used)
  float* s_h2  = sm + 5376;    // 4*64*16 (pitch 16, 13 used)
  float* s_w   = sm + 9472;    // up to 20864

  const int tid = threadIdx.x;
  const int n0 = blockIdx.x * 4;

  // stage images (coalesced)
  for (int i = tid; i < 1280; i += 256)
    s_img[i] = x[(size_t)n0 * 320 + i];
  // stage conv1 weights (pitch 25, coprime with 32) + bias
  for (int i = tid; i < 832; i += 256)
    s_w[i] = (i < 800) ? w1[i] : b1[i - 800];
  __syncthreads();

  // ---- conv1 + relu + pool: thread = (im, half, o); wave = one image
  {
    const int o = tid & 31, half = (tid >> 5) & 1, im = tid >> 6;
    float wr[25];
#pragma unroll
    for (int i = 0; i < 25; ++i) wr[i] = s_w[o * 25 + i];
    const float bia = s_w[800 + o];
    const float* ib = s_img + im * 320;
#pragma unroll
    for (int j = 0; j < 15; ++j) {
      const int tp = half * 15 + j, t0 = 2 * tp;
      float s0 = bia, s1 = bia;
#pragma unroll
      for (int kr = 0; kr < 5; ++kr) {
        const float* r = ib + kr * 64 + t0;   // broadcast reads (same addr per wave-half)
        const float c0 = r[0], c1 = r[1], c2 = r[2], c3 = r[3], c4 = r[4], c5 = r[5];
        const float* w = wr + kr * 5;
        s0 += c0 * w[0] + c1 * w[1] + c2 * w[2] + c3 * w[3] + c4 * w[4];
        s1 += c1 * w[0] + c2 * w[1] + c3 * w[2] + c4 * w[3] + c5 * w[4];
      }
      s_h1[im * 1024 + o * 32 + tp] = fmaxf(fmaxf(s0, s1), 0.f);
    }
  }
  __syncthreads();
  // stage conv2 weights, pitch 165 (165%32=5, coprime -> conflict-free lane reads)
  for (int i = tid; i < 10240; i += 256) {
    const int o = i / 160, r = i - o * 160;
    s_w[o * 165 + r] = w2[i];
  }
  if (tid < 64) s_w[10560 + tid] = b2[tid];
  __syncthreads();

  // ---- conv2 + relu + pool: thread = (im, o), full 13-wide row in registers
  {
    const int o = tid & 63, im = tid >> 6;
    float acc0[13], acc1[13];
    const float bia = s_w[10560 + o];
#pragma unroll
    for (int t = 0; t < 13; ++t) { acc0[t] = bia; acc1[t] = bia; }
    for (int ci = 0; ci < 32; ++ci) {
      const float* hr = s_h1 + im * 1024 + ci * 32;   // wave-broadcast row
      float r[30];
#pragma unroll
      for (int q = 0; q < 7; ++q) {
        const float4 v = *(const float4*)(hr + q * 4);
        r[q * 4 + 0] = v.x; r[q * 4 + 1] = v.y; r[q * 4 + 2] = v.z; r[q * 4 + 3] = v.w;
      }
      { const float2 v = *(const float2*)(hr + 28); r[28] = v.x; r[29] = v.y; }
      const float* w = s_w + o * 165 + ci * 5;
      const float w0 = w[0], w1_ = w[1], w2_ = w[2], w3_ = w[3], w4_ = w[4];
#pragma unroll
      for (int t = 0; t < 13; ++t) {
        const int t0 = 2 * t;
        acc0[t] += r[t0] * w0 + r[t0 + 1] * w1_ + r[t0 + 2] * w2_ + r[t0 + 3] * w3_ + r[t0 + 4] * w4_;
        acc1[t] += r[t0 + 1] * w0 + r[t0 + 2] * w1_ + r[t0 + 3] * w2_ + r[t0 + 4] * w3_ + r[t0 + 5] * w4_;
      }
    }
#pragma unroll
    for (int t = 0; t < 13; ++t)
      s_h2[im * 1024 + o * 16 + t] = fmaxf(fmaxf(acc0[t], acc1[t]), 0.f);
  }
  __syncthreads();

  // ---- conv3 + relu + pool: 2 chunks of 64 out-channels; thread = (im, oc)
  {
    const int oc = tid & 63, im3 = tid >> 6;
#pragma unroll 1
    for (int ch = 0; ch < 2; ++ch) {
      // stage 64x320 weights, pitch 325 (325%32=5, coprime)
      for (int i = tid; i < 20480; i += 256) {
        const int o = i / 320, r = i - o * 320;
        s_w[o * 325 + r] = w3[ch * 20480 + i];
      }
      if (tid < 64) s_w[20800 + tid] = b3[ch * 64 + tid];
      __syncthreads();
      {
        float acc[8];
        const float bia = s_w[20800 + oc];
#pragma unroll
        for (int t = 0; t < 8; ++t) acc[t] = bia;
        for (int ci = 0; ci < 64; ++ci) {
          const float* hr = s_h2 + im3 * 1024 + ci * 16;  // wave-broadcast row
          float r[12];
#pragma unroll
          for (int q = 0; q < 3; ++q) {
            const float4 v = *(const float4*)(hr + q * 4);
            r[q * 4 + 0] = v.x; r[q * 4 + 1] = v.y; r[q * 4 + 2] = v.z; r[q * 4 + 3] = v.w;
          }
          const float* w = s_w + oc * 325 + ci * 5;
          const float w0 = w[0], w1_ = w[1], w2_ = w[2], w3_ = w[3], w4_ = w[4];
#pragma unroll
          for (int t = 0; t < 8; ++t)
            acc[t] += r[t] * w0 + r[t + 1] * w1_ + r[t + 2] * w2_ + r[t + 3] * w3_ + r[t + 4] * w4_;
        }
        float4 ov;
        ov.x = fmaxf(fmaxf(acc[0], acc[1]), 0.f);
        ov.y = fmaxf(fmaxf(acc[2], acc[3]), 0.f);
        ov.z = fmaxf(fmaxf(acc[4], acc[5]), 0.f);
        ov.w = fmaxf(fmaxf(acc[6], acc[7]), 0.f);
        *(float4*)(H3 + (size_t)(n0 + im3) * 512 + (size_t)(ch * 64 + oc) * 4) = ov;
      }
      __syncthreads();
    }
  }
}

// ================= SOGC layer =================
// One block (256 thr = 4 waves) per batch element b.
// LDS: sH[62*DIN] | sG[62*33] | sP[62*64] | stv[620] | sti[620]
template <int DIN>
__global__ __launch_bounds__(256) void sogc_kernel(
    const float* __restrict__ Hin,   // (512, 62, DIN)
    const float* __restrict__ Wbn,   // (32, DIN)
    const float* __restrict__ gcw,   // (64, DIN)
    const float* __restrict__ gcb,   // (64)
    float* __restrict__ Hout)        // (512, 62, 64)
{
  extern __shared__ float sm[];
  float* sH  = sm;                    // 62*DIN
  float* sG  = sH + 62 * DIN;         // 62*33 (pitch 33: conflict-free column reads)
  float* sP  = sG + 62 * 33;          // 62*64
  float* stv = sP + 62 * 64;          // 620
  int*   sti = (int*)(stv + 620);     // 620

  const int b = blockIdx.x;
  const int tid = threadIdx.x;
  const int lane = tid & 63;
  const int wave = tid >> 6;
  constexpr int NI = DIN / 64;

  // phase 1: load H (float4, coalesced)
  const float* Hb = Hin + (size_t)b * (62 * DIN);
  for (int i = tid * 4; i < 62 * DIN; i += 1024)
    *(float4*)(sH + i) = *(const float4*)(Hb + i);
  __syncthreads();

  // phase 2: G = tanh(H @ Wbn^T). Wave owns k-rows; weight row lives in regs.
  for (int k = wave; k < 32; k += 4) {
    float wr[NI];
#pragma unroll
    for (int i = 0; i < NI; ++i) wr[i] = Wbn[k * DIN + i * 64 + lane];
    for (int e = 0; e < E_NODES; ++e) {
      float s = 0.f;
#pragma unroll
      for (int i = 0; i < NI; ++i) s += sH[e * DIN + i * 64 + lane] * wr[i];
#pragma unroll
      for (int off = 32; off; off >>= 1) s += __shfl_xor(s, off);
      if (lane == 0) {
        // tanh(x) = 1 - 2/(e^{2x}+1); saturates correctly at +-inf
        sG[e * 33 + k] = 1.f - 2.f / (__expf(2.f * s) + 1.f);
      }
    }
  }
  __syncthreads();

  // phase 3: scores -> softmax -> top-10 (per wave per row)
  for (int e = wave; e < E_NODES; e += 4) {
    float sc = -1e30f;
    if (lane < E_NODES) {
      float s = 0.f;
#pragma unroll
      for (int k = 0; k < 32; ++k) s += sG[e * 33 + k] * sG[lane * 33 + k];
      sc = s;
    }
    float mx = sc;
#pragma unroll
    for (int off = 32; off; off >>= 1) mx = fmaxf(mx, __shfl_xor(mx, off));
    float p = (lane < E_NODES) ? __expf(sc - mx) : 0.f;
    float sum = p;
#pragma unroll
    for (int off = 32; off; off >>= 1) sum += __shfl_xor(sum, off);
    p = p / sum;

    float v = (lane < E_NODES) ? p : -1.f;
#pragma unroll 1
    for (int it = 0; it < TOPK; ++it) {
      float bv = v; int bi = lane;
#pragma unroll
      for (int off = 32; off; off >>= 1) {
        const float ov = __shfl_xor(bv, off);
        const int   oi = __shfl_xor(bi, off);
        if (ov > bv || (ov == bv && oi < bi)) { bv = ov; bi = oi; }  // lax.top_k tie-break
      }
      if (lane == 0) { stv[e * 10 + it] = bv; sti[e * 10 + it] = bi; }
      if (lane == bi) v = -1.f;
    }
  }
  __syncthreads();

  // phase 4: P = H @ gcw^T (62x64). Wave owns o-columns; gcw row in regs.
  for (int o = wave; o < 64; o += 4) {
    float wr[NI];
#pragma unroll
    for (int i = 0; i < NI; ++i) wr[i] = gcw[o * DIN + i * 64 + lane];
    for (int f = 0; f < E_NODES; ++f) {
      float s = 0.f;
#pragma unroll
      for (int i = 0; i < NI; ++i) s += sH[f * DIN + i * 64 + lane] * wr[i];
#pragma unroll
      for (int off = 32; off; off >>= 1) s += __shfl_xor(s, off);
      if (lane == 0) sP[f * 64 + o] = s;
    }
  }
  __syncthreads();

  // phase 5: out[e][o] = relu(b[o] + sum_j val_j * P[idx_j][o])
  for (int e = wave; e < E_NODES; e += 4) {
    float acc = gcb[lane];
#pragma unroll
    for (int j = 0; j < TOPK; ++j)
      acc += stv[e * 10 + j] * sP[sti[e * 10 + j] * 64 + lane];
    Hout[((size_t)b * E_NODES + e) * 64 + lane] = fmaxf(acc, 0.f);
  }
}

// ================= classifier =================
__global__ __launch_bounds__(256) void cls_kernel(
    const float* __restrict__ Hs, const float* __restrict__ cw,
    const float* __restrict__ cb, float* __restrict__ out)
{
  const int b = blockIdx.x, tid = threadIdx.x;
  const int lane = tid & 63, wave = tid >> 6;
  const float* h = Hs + (size_t)b * 3968;
  float acc[4] = {0.f, 0.f, 0.f, 0.f};
  for (int i = tid; i < 3968; i += 256) {
    const float hv = h[i];
#pragma unroll
    for (int n = 0; n < 4; ++n) acc[n] += hv * cw[n * 3968 + i];
  }
  __shared__ float sp[4][4];
#pragma unroll
  for (int n = 0; n < 4; ++n) {
    float s = acc[n];
#pragma unroll
    for (int off = 32; off; off >>= 1) s += __shfl_xor(s, off);
    if (lane == 0) sp[wave][n] = s;
  }
  __syncthreads();
  if (tid < 4)
    out[b * 4 + tid] = cb[tid] + sp[0][tid] + sp[1][tid] + sp[2][tid] + sp[3][tid];
}

// ================= launch =================
extern "C" void kernel_launch(void* const* d_in, const int* in_sizes, int n_in,
                              void* d_out, int out_size, void* d_ws, size_t ws_size,
                              hipStream_t stream) {
  const float* x      = (const float*)d_in[0];
  const float* c1w    = (const float*)d_in[1];
  const float* c1b    = (const float*)d_in[2];
  const float* c2w    = (const float*)d_in[3];
  const float* c2b    = (const float*)d_in[4];
  const float* c3w    = (const float*)d_in[5];
  const float* c3b    = (const float*)d_in[6];
  const float* Wbn1   = (const float*)d_in[7];
  const float* gc1w   = (const float*)d_in[8];
  const float* gc1b   = (const float*)d_in[9];
  const float* Wbn2   = (const float*)d_in[10];
  const float* gc2w   = (const float*)d_in[11];
  const float* gc2b   = (const float*)d_in[12];
  const float* Wbn3   = (const float*)d_in[13];
  const float* gc3w   = (const float*)d_in[14];
  const float* gc3b   = (const float*)d_in[15];
  const float* clsw   = (const float*)d_in[16];
  const float* clsb   = (const float*)d_in[17];
  float* out = (float*)d_out;

  float* wsf = (float*)d_ws;
  float* H3  = wsf;                         // 31744*512 = 16,252,928 floats
  float* Hs1 = wsf + (size_t)16252928;      // 512*62*64 = 2,031,616
  float* Hs2 = Hs1 + (size_t)2031616;       // total ws use ~77.5 MB

  const int SOGC1_BYTES = (62 * 512 + 62 * 33 + 62 * 64 + 620) * 4 + 620 * 4;  // 155,992
  const int SOGC2_BYTES = (62 * 64 + 62 * 33 + 62 * 64 + 620) * 4 + 620 * 4;   // 44,888

  // opt-in to >64KB dynamic LDS (idempotent, host-side, capture-safe)
  (void)hipFuncSetAttribute((const void*)conv_chain_kernel,
                            hipFuncAttributeMaxDynamicSharedMemorySize, CONV_LDS_BYTES);
  (void)hipFuncSetAttribute((const void*)sogc_kernel<512>,
                            hipFuncAttributeMaxDynamicSharedMemorySize, SOGC1_BYTES);
  (void)hipFuncSetAttribute((const void*)sogc_kernel<64>,
                            hipFuncAttributeMaxDynamicSharedMemorySize, SOGC2_BYTES);

  conv_chain_kernel<<<7936, 256, CONV_LDS_BYTES, stream>>>(
      x, c1w, c1b, c2w, c2b, c3w, c3b, H3);
  sogc_kernel<512><<<512, 256, SOGC1_BYTES, stream>>>(H3, Wbn1, gc1w, gc1b, Hs1);
  sogc_kernel<64><<<512, 256, SOGC2_BYTES, stream>>>(Hs1, Wbn2, gc2w, gc2b, Hs2);
  sogc_kernel<64><<<512, 256, SOGC2_BYTES, stream>>>(Hs2, Wbn3, gc3w, gc3b, Hs1);
  cls_kernel<<<512, 256, 0, stream>>>(Hs1, clsw, clsb, out);
}